// Round 12
// baseline (26978.802 us; speedup 1.0000x reference)
//
#include <hip/hip_runtime.h>
#include <hip/hip_bf16.h>

// SimpleLSTM persistent cooperative kernel.
// R12: 16 WGs x 512 threads (was 64x256). Rationale (R11 probe): clock >=1.2GHz
// -> 13us/step is ~30K cycles of genuine serialized cost; candidates that
// scale with WG count: (a) 64 atomic arrivals + 128 pollers on ONE line,
// (b) 4MB/step uncached h fan-out (262K 16B requests). This round cuts
// (a) 4x (16 arrivals / 64 pollers) and (b) 4x (h staged ONCE per WG into
// LDS, 4 h-waves consume from LDS; 1MB/step fabric).
// Structure per WG (8 waves): waves 0-3 = x-half (gate q=sub, 32 cols,
// K=x512, W_ih in 128 VGPRs), waves 4-7 = h-half (same vrows, K=h512, W_hh).
// Per step: x-GEMM -> xpart(LDS) || poll+stage h->hstage(LDS) | bar1 |
// h-MFMA (LDS frag-major, conflict-free) -> hpart | bar2 | elementwise on all
// 512 threads -> h agent-store / out | bar3 (drains store acks) | tid0
// atomicAdd counter (16 arrivals/step).

#define B_ 64
#define T_ 1024
#define I_ 512
#define H_ 512
#define NWG 16

typedef __attribute__((ext_vector_type(8))) short bf16x8;
typedef __attribute__((ext_vector_type(4))) float f32x4;

__device__ __forceinline__ unsigned cvt_pk_bf16(float lo, float hi) {
  unsigned r;
  asm volatile("v_cvt_pk_bf16_f32 %0, %1, %2" : "=v"(r) : "v"(lo), "v"(hi));
  return r;
}

__device__ __forceinline__ float sigf(float x) { return 1.0f / (1.0f + __expf(-x)); }
// NaN-safe tanh: saturates to +/-1 for large |x|
__device__ __forceinline__ float tanh_fast(float x) { return 1.0f - 2.0f / (__expf(2.0f * x) + 1.0f); }

__global__ __launch_bounds__(512, 2) void lstm_seq(
    const float* __restrict__ x, const float* __restrict__ Wih,
    const float* __restrict__ Whh, const float* __restrict__ bih,
    const float* __restrict__ bhh, float* __restrict__ out,
    unsigned* __restrict__ counter, unsigned short* __restrict__ hbuf)
{
  __shared__ float xpart[128 * 66];          // [vrow][batch], pitch 66 (33KB)
  __shared__ float hpart[128 * 66];          // [vrow][batch] (33KB)
  __shared__ unsigned short hstage[64 * 512]; // frag-major [fid][lane][8] (64KB)

  const int tid  = threadIdx.x;
  const int wg   = blockIdx.x;               // 0..15, owns h-cols [32wg,32wg+32)
  const int wave = tid >> 6;                 // 0..7
  const int lane = tid & 63;
  const int kh   = wave >> 2;                // 0: x-half, 1: h-half
  const int sub  = wave & 3;                 // = gate q (i,f,g,o)
  const int l15  = lane & 15;
  const int lg   = lane >> 4;                // 0..3

  // ---- W slice into registers as bf16 (once). Wave covers gate q=sub,
  // cols wg*32 + nt*16 + l15, full K=512 of its half. 128 VGPRs. ----
  bf16x8 wreg[2][16];                        // [n-tile][k-tile]
  float biasv[2];
  {
    const float* Wsrc = (kh == 0) ? Wih : Whh;
    #pragma unroll
    for (int nt = 0; nt < 2; ++nt) {
      const int grow = sub * 512 + wg * 32 + nt * 16 + l15;
      biasv[nt] = bih[grow] + bhh[grow];
      #pragma unroll
      for (int kt = 0; kt < 16; ++kt) {
        const float* p = Wsrc + (size_t)grow * 512 + kt * 32 + lg * 8;
        union { bf16x8 v8; unsigned u[4]; } wv;
        #pragma unroll
        for (int q = 0; q < 4; ++q) wv.u[q] = cvt_pk_bf16(p[2*q], p[2*q+1]);
        wreg[nt][kt] = wv.v8;
      }
    }
  }

  // elementwise mapping: thread -> (batch eb, cols ec4..ec4+3)
  const int eb  = tid >> 3;                  // 0..63
  const int ec4 = (tid & 7) * 4;             // 0,4,..,28
  float cst[4] = {0.f, 0.f, 0.f, 0.f};

  for (int t = 0; t < T_; ++t) {
    f32x4 acc[4][2] = {};                    // [m-tile][n-tile]

    if (kh == 0) {
      // ---- x-half GEMM: A[b][k] = x[b][t][k] (fp32 -> bf16 in-reg) ----
      const float* xt = x + (size_t)t * I_;
      #pragma unroll
      for (int kt = 0; kt < 16; ++kt) {
        #pragma unroll
        for (int mt = 0; mt < 4; ++mt) {
          const int b = mt * 16 + l15;
          const float* p = xt + (size_t)b * ((size_t)T_ * I_) + kt * 32 + lg * 8;
          f32x4 f0 = *(const f32x4*)p;
          f32x4 f1 = *(const f32x4*)(p + 4);
          union { bf16x8 v8; unsigned u[4]; } av;
          av.u[0] = cvt_pk_bf16(f0.x, f0.y);
          av.u[1] = cvt_pk_bf16(f0.z, f0.w);
          av.u[2] = cvt_pk_bf16(f1.x, f1.y);
          av.u[3] = cvt_pk_bf16(f1.z, f1.w);
          #pragma unroll
          for (int nt = 0; nt < 2; ++nt)
            acc[mt][nt] = __builtin_amdgcn_mfma_f32_16x16x32_bf16(av.v8, wreg[nt][kt], acc[mt][nt], 0, 0, 0);
        }
      }
      // write x partials (+ bias) to LDS
      #pragma unroll
      for (int mt = 0; mt < 4; ++mt)
        #pragma unroll
        for (int nt = 0; nt < 2; ++nt) {
          const int v = sub * 32 + nt * 16 + l15;
          const int bb = mt * 16 + lg * 4;
          #pragma unroll
          for (int r = 0; r < 4; ++r) xpart[v * 66 + bb + r] = acc[mt][nt][r] + biasv[nt];
        }
    } else if (t > 0) {
      // ---- poll: all WGs finished step t-1 (16 arrivals on one counter) ----
      const unsigned tgt = (unsigned)NWG * (unsigned)t;
      float j0 = 1.0f, j1 = 1.0001f;
      int guard = 0;
      for (;;) {
        unsigned tmp = 0;
        if (lane == 0)
          tmp = __hip_atomic_load(counter, __ATOMIC_RELAXED, __HIP_MEMORY_SCOPE_AGENT);
        unsigned sv = __builtin_amdgcn_readfirstlane(tmp);
        if (sv >= tgt) break;
        #pragma unroll
        for (int u = 0; u < 4; ++u) {       // small backoff, keeps issue alive
          j0 = __builtin_fmaf(j0, 1.0000001f, 1e-32f);
          j1 = __builtin_fmaf(j1, 0.9999999f, 1e-32f);
        }
        if (++guard > (1 << 24)) break;     // safety valve
      }
      asm volatile("" :: "v"(j0), "v"(j1));
      asm volatile("" ::: "memory");        // don't hoist h loads above the spin
      __builtin_amdgcn_sched_barrier(0);

      // ---- stage h into LDS ONCE per WG (this wave: 16 of 64 fragments).
      // Fragment fid=(kt*4+mt): LDS holds exactly the bf16x8 lane fragment ->
      // later ds_read_b128 is fully coalesced (conflict-free). ----
      bf16x8 hr[16];
      const char* hb = (const char*)(hbuf + (size_t)(t & 1) * (B_ * H_));
      #pragma unroll
      for (int i = 0; i < 16; ++i) {
        const int fid = sub * 16 + i;
        const int kt = fid >> 2, mt = fid & 3;
        const char* p = hb + (size_t)((mt * 16 + l15) * 512 + kt * 32 + lg * 8) * 2;
        asm volatile("global_load_dwordx4 %0, %1, off sc0 sc1"
                     : "=v"(hr[i]) : "v"(p));
      }
      asm volatile("s_waitcnt vmcnt(8)");   // first 8 loads done
      __builtin_amdgcn_sched_barrier(0);
      #pragma unroll
      for (int i = 0; i < 8; ++i) {
        const int fid = sub * 16 + i;
        *(bf16x8*)&hstage[(fid * 64 + lane) * 8] = hr[i];
      }
      asm volatile("s_waitcnt vmcnt(0)");   // rest done
      __builtin_amdgcn_sched_barrier(0);
      #pragma unroll
      for (int i = 8; i < 16; ++i) {
        const int fid = sub * 16 + i;
        *(bf16x8*)&hstage[(fid * 64 + lane) * 8] = hr[i];
      }
    }

    __syncthreads();   // bar1: xpart written, hstage fully staged

    if (kh == 1) {
      if (t > 0) {
        // ---- h-half GEMM from LDS (conflict-free frag-major reads) ----
        #pragma unroll
        for (int kt = 0; kt < 16; ++kt) {
          #pragma unroll
          for (int mt = 0; mt < 4; ++mt) {
            bf16x8 av = *(const bf16x8*)&hstage[((kt * 4 + mt) * 64 + lane) * 8];
            #pragma unroll
            for (int nt = 0; nt < 2; ++nt)
              acc[mt][nt] = __builtin_amdgcn_mfma_f32_16x16x32_bf16(av, wreg[nt][kt], acc[mt][nt], 0, 0, 0);
          }
        }
      }
      // write h partials (zeros at t==0: h0 = 0)
      #pragma unroll
      for (int mt = 0; mt < 4; ++mt)
        #pragma unroll
        for (int nt = 0; nt < 2; ++nt) {
          const int v = sub * 32 + nt * 16 + l15;
          const int bb = mt * 16 + lg * 4;
          #pragma unroll
          for (int r = 0; r < 4; ++r) hpart[v * 66 + bb + r] = acc[mt][nt][r];
        }
    }

    __syncthreads();   // bar2: hpart ready

    // ---- elementwise LSTM cell update: all 512 threads, 4 cells each ----
    {
      float hv[4];
      #pragma unroll
      for (int j = 0; j < 4; ++j) {
        const int c = ec4 + j;
        float gi = xpart[(0 * 32 + c) * 66 + eb] + hpart[(0 * 32 + c) * 66 + eb];
        float gf = xpart[(1 * 32 + c) * 66 + eb] + hpart[(1 * 32 + c) * 66 + eb];
        float gg = xpart[(2 * 32 + c) * 66 + eb] + hpart[(2 * 32 + c) * 66 + eb];
        float go = xpart[(3 * 32 + c) * 66 + eb] + hpart[(3 * 32 + c) * 66 + eb];
        float cn = sigf(gf) * cst[j] + sigf(gi) * tanh_fast(gg);
        cst[j] = cn;
        hv[j] = sigf(go) * tanh_fast(cn);
      }
      if (t == T_ - 1) {
        f32x4 o4; o4.x = hv[0]; o4.y = hv[1]; o4.z = hv[2]; o4.w = hv[3];
        *(f32x4*)&out[(size_t)eb * H_ + wg * 32 + ec4] = o4;
      } else {
        unsigned short* hdst = hbuf + (size_t)((t + 1) & 1) * (B_ * H_);
        const unsigned lo = cvt_pk_bf16(hv[0], hv[1]);
        const unsigned hi = cvt_pk_bf16(hv[2], hv[3]);
        const unsigned long long pk = ((unsigned long long)hi << 32) | lo;
        __hip_atomic_store((unsigned long long*)(hdst + (size_t)eb * H_ + wg * 32 + ec4),
                           pk, __ATOMIC_RELAXED, __HIP_MEMORY_SCOPE_AGENT);
      }
    }

    // bar3: __syncthreads drains vmcnt(0) in every wave -> all h stores are
    // at the coherence point before tid0's release below.
    __syncthreads();
    if (tid == 0 && t < T_ - 1) {
      __hip_atomic_fetch_add(counter, 1u, __ATOMIC_RELAXED, __HIP_MEMORY_SCOPE_AGENT);
    }
  }
}

extern "C" void kernel_launch(void* const* d_in, const int* in_sizes, int n_in,
                              void* d_out, int out_size, void* d_ws, size_t ws_size,
                              hipStream_t stream) {
  const float* x   = (const float*)d_in[0];
  const float* Wih = (const float*)d_in[1];
  const float* Whh = (const float*)d_in[2];
  const float* bih = (const float*)d_in[3];
  const float* bhh = (const float*)d_in[4];
  float* out = (float*)d_out;

  // ws layout: [0,1024): barrier counter (u32, zeroed each launch)
  //            [1024, 1024+256K): h double buffer, bf16 [2][64][512]
  unsigned* counter = (unsigned*)d_ws;
  unsigned short* hbuf = (unsigned short*)((char*)d_ws + 1024);

  hipMemsetAsync(d_ws, 0, 1024, stream);
  lstm_seq<<<NWG, 512, 0, stream>>>(x, Wih, Whh, bih, bhh, out, counter, hbuf);
}